// Round 1
// baseline (233.011 us; speedup 1.0000x reference)
//
#include <hip/hip_runtime.h>

#define TM 128
#define TN 256
#define BK 128   // fp8 bytes per K-slab = one 16x16x128 MFMA k-step

typedef float f32x4 __attribute__((ext_vector_type(4)));
typedef int   i32x4 __attribute__((ext_vector_type(4)));
typedef int   i32x8 __attribute__((ext_vector_type(8)));

// E8M0 scales: value = 2^(byte-127). A-scale = 2^0; B holds cent*2^6, B-scale = 2^-6.
#define SCALE_A 127
#define SCALE_B 121

__device__ __forceinline__ unsigned char f2fp8(float f) {
    int p = __builtin_amdgcn_cvt_pk_fp8_f32(f, f, 0, false);
    return (unsigned char)(p & 0xff);
}

// ---- prep_x: x (B,1024) fp32 -> x8 fp8 row-major, x2[b] = sum(x^2) (exact fp32) ----
__global__ __launch_bounds__(256) void prep_x(const float* __restrict__ x,
                                              unsigned int* __restrict__ x8,
                                              float* __restrict__ x2) {
    const int b = blockIdx.x;
    const int t = threadIdx.x;
    const float4 v = ((const float4*)(x + (size_t)b * 1024))[t];
    float sum = v.x * v.x + v.y * v.y + v.z * v.z + v.w * v.w;
    int p = __builtin_amdgcn_cvt_pk_fp8_f32(v.x, v.y, 0, false);
    p = __builtin_amdgcn_cvt_pk_fp8_f32(v.z, v.w, p, true);
    x8[(size_t)b * 256 + t] = (unsigned int)p;
    #pragma unroll
    for (int o = 32; o > 0; o >>= 1) sum += __shfl_down(sum, o, 64);
    __shared__ float red[4];
    if ((t & 63) == 0) red[t >> 6] = sum;
    __syncthreads();
    if (t == 0) x2[b] = red[0] + red[1] + red[2] + red[3];
}

// ---- init_s: s[c] = bias[c] (c2 accumulated atomically by prep_w) ----
__global__ __launch_bounds__(256) void init_s(const float* __restrict__ bias,
                                              float* __restrict__ s, int C) {
    int i = blockIdx.x * 256 + threadIdx.x;
    if (i < C) s[i] = bias[i];
}

// ---- prep_w: cent[4q+r][d] = W[r*1024+d][q]; c8 = fp8(cent*64) (C x D row-major);
//      s[c] += ||cent_c||^2 (exact fp32, from fp32 W). LDS-tiled transpose. ----
__global__ __launch_bounds__(256) void prep_w(const float* __restrict__ W,
                                              unsigned char* __restrict__ c8,
                                              float* __restrict__ s) {
    __shared__ float tile[64][65];
    __shared__ float cred[4][64];
    const int tid = threadIdx.x;
    const int tx = tid & 63;
    const int ty = tid >> 6;
    const int q0 = blockIdx.x * 64;
    const int e0 = blockIdx.y * 64;      // e = r*1024 + d
    const int r  = e0 >> 10;
    const int d0 = e0 & 1023;

    float csum = 0.f;
    #pragma unroll
    for (int p = 0; p < 16; p++) {
        const int er = p * 4 + ty;
        const float v = W[(size_t)(e0 + er) * 1024 + q0 + tx];
        tile[er][tx] = v;
        csum += v * v;
    }
    cred[ty][tx] = csum;
    __syncthreads();
    if (ty == 0) {
        atomicAdd(&s[4 * (q0 + tx) + r],
                  cred[0][tx] + cred[1][tx] + cred[2][tx] + cred[3][tx]);
    }
    #pragma unroll
    for (int p = 0; p < 16; p++) {
        const int q = q0 + p * 4 + ty;
        const float v = tile[tx][p * 4 + ty];
        c8[(size_t)(4 * q + r) * 1024 + d0 + tx] = f2fp8(v * 64.f);
    }
}

// ---- gemm_bt: out[m][n] = 2*sum_k A[m][k]*Bt[n][k] - x2[m] - s[n] ----
// MX-scaled fp8 16x16x128. Block tile 128x256, 4 waves, each wave owns 64x128.
// R5 changes vs R4-best (199.3 us):
//  (1) Counted-vmcnt software pipeline (T3/T4): double-buffered LDS (96 KB ->
//      1 block/CU), raw s_barrier, asm s_waitcnt vmcnt(12) — next slab's 12
//      global_load_lds stay in flight across the barrier under the current
//      slab's 32 MFMAs. Prior "dbuf neutral" used __syncthreads (vmcnt(0)
//      drain) which is the known-neutral variant; counted-N is the lever.
//  (2) Operand-swapped MFMA -> transposed C fragment: each lane holds 4
//      consecutive COLUMNS -> f32x4 nontemporal stores (32 dwordx4/thread
//      instead of 128 dword), and out-stream no longer thrashes L2 where
//      c8 (4 MB) + A-stripe (1 MB) must stay resident.
// XOR-swizzled LDS chunks unchanged (0 conflicts, verified in prior session).
__global__ __launch_bounds__(256, 1) void gemm_bt(const unsigned char* __restrict__ A,
                                                  const unsigned char* __restrict__ Bt,
                                                  const float* __restrict__ x2,
                                                  const float* __restrict__ s,
                                                  float* __restrict__ out,
                                                  int M, int N, int K) {
    __shared__ unsigned char la[2 * TM * BK];   // 32 KB (double-buffered)
    __shared__ unsigned char lb[2 * TN * BK];   // 64 KB (double-buffered)

    const int tid  = threadIdx.x;
    const int wave = tid >> 6;
    const int lane = tid & 63;
    const int quad = lane >> 4;
    const int l16  = lane & 15;
    const int wm   = wave & 1;     // m half: 64 rows
    const int wn   = wave >> 1;    // n half: 128 cols

    // XCD m-stripe swizzle (m-tiles = M/TM = 64, n-tiles = N/TN = 16)
    const int flat = blockIdx.x;
    const int xcd  = flat & 7;
    const int idx  = flat >> 3;
    const int mt   = (idx & 7) | (xcd << 3);
    const int nt   = idx >> 3;
    const int tile_m = mt * TM;
    const int tile_n = nt * TN;

    // staging: lane -> row (base + lane/8), slot (lane&7); source chunk XOR-swizzled
    const int srow8 = lane >> 3;
    const int gcol  = ((lane & 7) ^ srow8) * 16;
    const unsigned char* gA = A  + (size_t)(tile_m + wave * 32 + srow8) * K + gcol;
    const unsigned char* gB = Bt + (size_t)(tile_n + wave * 64 + srow8) * K + gcol;

    f32x4 acc[4][8];
    #pragma unroll
    for (int i = 0; i < 4; i++)
        #pragma unroll
        for (int j = 0; j < 8; j++) acc[i][j] = (f32x4){0.f, 0.f, 0.f, 0.f};

    const int sw = l16 & 7;
    const int slot_lo = ((2 * quad) ^ sw) * 16;
    const int slot_hi = ((2 * quad + 1) ^ sw) * 16;

    // stage one K-slab (byte offset kt) into buffer `buf`
    auto stage = [&](int kt, int buf) {
        unsigned char* lab = la + buf * (TM * BK);
        unsigned char* lbb = lb + buf * (TN * BK);
        #pragma unroll
        for (int i = 0; i < 4; i++) {
            __builtin_amdgcn_global_load_lds(
                (const __attribute__((address_space(1))) void*)(gA + (size_t)(i * 8) * K + kt),
                (__attribute__((address_space(3))) void*)(lab + (wave * 32 + i * 8) * BK),
                16, 0, 0);
        }
        #pragma unroll
        for (int j = 0; j < 8; j++) {
            __builtin_amdgcn_global_load_lds(
                (const __attribute__((address_space(1))) void*)(gB + (size_t)(j * 8) * K + kt),
                (__attribute__((address_space(3))) void*)(lbb + (wave * 64 + j * 8) * BK),
                16, 0, 0);
        }
    };

    const int nkt = K / BK;   // 8
    stage(0, 0);
    int cur = 0;
    for (int t = 0; t < nkt; ++t) {
        if (t + 1 < nkt) {
            stage((t + 1) * BK, cur ^ 1);
            // 12 new loads outstanding; wait until only those remain -> slab t resident
            asm volatile("s_waitcnt vmcnt(12)" ::: "memory");
        } else {
            asm volatile("s_waitcnt vmcnt(0)" ::: "memory");
        }
        __builtin_amdgcn_s_barrier();   // all waves' slab-t loads now in LDS

        const unsigned char* pa_row = la + cur * (TM * BK) + (wm * 64 + l16) * BK;
        const unsigned char* pb_row = lb + cur * (TN * BK) + (wn * 128 + l16) * BK;

        i32x8 af[4];
        #pragma unroll
        for (int i = 0; i < 4; i++) {
            i32x4 lo = *(const i32x4*)(pa_row + i * 16 * BK + slot_lo);
            i32x4 hi = *(const i32x4*)(pa_row + i * 16 * BK + slot_hi);
            af[i] = __builtin_shufflevector(lo, hi, 0, 1, 2, 3, 4, 5, 6, 7);
        }
        #pragma unroll
        for (int j = 0; j < 8; j++) {
            i32x4 lo = *(const i32x4*)(pb_row + j * 16 * BK + slot_lo);
            i32x4 hi = *(const i32x4*)(pb_row + j * 16 * BK + slot_hi);
            i32x8 bf = __builtin_shufflevector(lo, hi, 0, 1, 2, 3, 4, 5, 6, 7);
            #pragma unroll
            for (int i = 0; i < 4; i++)
                // swapped operands: D fragment transposed (row=n, col=m); scales swap too
                acc[i][j] = __builtin_amdgcn_mfma_scale_f32_16x16x128_f8f6f4(
                    bf, af[i], acc[i][j], 0, 0, 0, SCALE_B, 0, SCALE_A);
        }

        __builtin_amdgcn_s_barrier();   // buf `cur` free for reuse next iteration
        cur ^= 1;
    }

    // epilogue (transposed fragment): col = lane&15 -> m, row = quad*4 + rr -> n
    float xm[4];
    #pragma unroll
    for (int i = 0; i < 4; i++)
        xm[i] = x2[tile_m + wm * 64 + i * 16 + l16];
    #pragma unroll
    for (int j = 0; j < 8; j++) {
        const int n0 = tile_n + wn * 128 + j * 16 + quad * 4;
        const f32x4 sv = *(const f32x4*)(s + n0);
        #pragma unroll
        for (int i = 0; i < 4; i++) {
            const int m = tile_m + wm * 64 + i * 16 + l16;
            f32x4 v;
            #pragma unroll
            for (int rr = 0; rr < 4; rr++)
                v[rr] = 2.f * acc[i][j][rr] - xm[i] - sv[rr];
            __builtin_nontemporal_store(v, (f32x4*)(out + (size_t)m * N + n0));
        }
    }
}

extern "C" void kernel_launch(void* const* d_in, const int* in_sizes, int n_in,
                              void* d_out, int out_size, void* d_ws, size_t ws_size,
                              hipStream_t stream) {
    const float* x    = (const float*)d_in[0];
    const float* w    = (const float*)d_in[1];
    const float* bias = (const float*)d_in[2];
    float* out = (float*)d_out;

    const int C = in_sizes[2];              // 4096
    const int D = in_sizes[1] / C;          // 1024
    const int B = in_sizes[0] / D;          // 8192

    unsigned char* x8 = (unsigned char*)d_ws;              // B*D fp8 = 8 MB
    unsigned char* c8 = x8 + (size_t)B * D;                // C*D fp8 = 4 MB
    float* x2 = (float*)(c8 + (size_t)C * D);              // B fp32
    float* s  = x2 + B;                                    // C fp32

    init_s<<<(C + 255) / 256, 256, 0, stream>>>(bias, s, C);
    prep_w<<<dim3(D / 64, C / 64), 256, 0, stream>>>(w, c8, s);
    prep_x<<<B, 256, 0, stream>>>(x, (unsigned int*)x8, x2);
    const int nblocks = (B / TM) * (C / TN);
    gemm_bt<<<nblocks, 256, 0, stream>>>(x8, c8, x2, s, out, B, C, D);
}

// Round 2
// 230.132 us; speedup vs baseline: 1.0125x; 1.0125x over previous
//
#include <hip/hip_runtime.h>

#define TM 128
#define TN 128
#define BK 128   // fp8 bytes per K-slab = one 16x16x128 MFMA k-step

typedef float f32x4 __attribute__((ext_vector_type(4)));
typedef int   i32x4 __attribute__((ext_vector_type(4)));
typedef int   i32x8 __attribute__((ext_vector_type(8)));

// E8M0 scales: value = 2^(byte-127). A-scale = 2^0; B holds cent*2^6, B-scale = 2^-6.
#define SCALE_A 127
#define SCALE_B 121

__device__ __forceinline__ unsigned char f2fp8(float f) {
    int p = __builtin_amdgcn_cvt_pk_fp8_f32(f, f, 0, false);
    return (unsigned char)(p & 0xff);
}

// ---- prep_x: x (B,1024) fp32 -> x8 fp8 row-major, x2[b] = sum(x^2) (exact fp32) ----
__global__ __launch_bounds__(256) void prep_x(const float* __restrict__ x,
                                              unsigned int* __restrict__ x8,
                                              float* __restrict__ x2) {
    const int b = blockIdx.x;
    const int t = threadIdx.x;
    const float4 v = ((const float4*)(x + (size_t)b * 1024))[t];
    float sum = v.x * v.x + v.y * v.y + v.z * v.z + v.w * v.w;
    int p = __builtin_amdgcn_cvt_pk_fp8_f32(v.x, v.y, 0, false);
    p = __builtin_amdgcn_cvt_pk_fp8_f32(v.z, v.w, p, true);
    x8[(size_t)b * 256 + t] = (unsigned int)p;
    #pragma unroll
    for (int o = 32; o > 0; o >>= 1) sum += __shfl_down(sum, o, 64);
    __shared__ float red[4];
    if ((t & 63) == 0) red[t >> 6] = sum;
    __syncthreads();
    if (t == 0) x2[b] = red[0] + red[1] + red[2] + red[3];
}

// ---- prep_w: cent[4q+r][d] = W[r*1024+d][q]; c8 = fp8(cent*64) (C x D row-major);
//      s[c] += ||cent_c||^2 (exact fp32, from fp32 W; s pre-zeroed by memset). ----
__global__ __launch_bounds__(256) void prep_w(const float* __restrict__ W,
                                              unsigned char* __restrict__ c8,
                                              float* __restrict__ s) {
    __shared__ float tile[64][65];
    __shared__ float cred[4][64];
    const int tid = threadIdx.x;
    const int tx = tid & 63;
    const int ty = tid >> 6;
    const int q0 = blockIdx.x * 64;
    const int e0 = blockIdx.y * 64;      // e = r*1024 + d
    const int r  = e0 >> 10;
    const int d0 = e0 & 1023;

    float csum = 0.f;
    #pragma unroll
    for (int p = 0; p < 16; p++) {
        const int er = p * 4 + ty;
        const float v = W[(size_t)(e0 + er) * 1024 + q0 + tx];
        tile[er][tx] = v;
        csum += v * v;
    }
    cred[ty][tx] = csum;
    __syncthreads();
    if (ty == 0) {
        atomicAdd(&s[4 * (q0 + tx) + r],
                  cred[0][tx] + cred[1][tx] + cred[2][tx] + cred[3][tx]);
    }
    #pragma unroll
    for (int p = 0; p < 16; p++) {
        const int q = q0 + p * 4 + ty;
        const float v = tile[tx][p * 4 + ty];
        c8[(size_t)(4 * q + r) * 1024 + d0 + tx] = f2fp8(v * 64.f);
    }
}

// ---- gemm_bt: out[m][n] = 2*sum_k A[m][k]*Bt[n][k] - x2[m] - s[n] - bias[n] ----
// R6 vs R5 (gemm 82 us, MfmaUtil 15.9%, Occ 10.5% = 1 block/CU):
//  R5's 96 KB dbuf starved the CU: 1 wave/SIMD -> no TLP to hide ds_read
//  latency or barrier sync. Shrink to 128x128 dbuf (64 KB LDS, 148 VGPR) ->
//  2 independent blocks/CU (8 waves, 2/SIMD): one block computes while the
//  other barriers. KEEP counted-vmcnt pipeline (vmcnt(8), raw s_barrier) and
//  transposed-fragment f32x4 nontemporal epilogue. ADD setprio(1) around the
//  MFMA cluster (T5: pays off once waves have role diversity).
__global__ __launch_bounds__(256, 2) void gemm_bt(const unsigned char* __restrict__ A,
                                                  const unsigned char* __restrict__ Bt,
                                                  const float* __restrict__ x2,
                                                  const float* __restrict__ s,
                                                  const float* __restrict__ bias,
                                                  float* __restrict__ out,
                                                  int M, int N, int K) {
    __shared__ unsigned char la[2 * TM * BK];   // 32 KB (double-buffered)
    __shared__ unsigned char lb[2 * TN * BK];   // 32 KB (double-buffered)

    const int tid  = threadIdx.x;
    const int wave = tid >> 6;
    const int lane = tid & 63;
    const int quad = lane >> 4;
    const int l16  = lane & 15;
    const int wm   = wave & 1;     // m half: 64 rows
    const int wn   = wave >> 1;    // n half: 64 cols

    // XCD m-stripe swizzle (m-tiles = M/TM = 64, n-tiles = N/TN = 32)
    const int flat = blockIdx.x;    // 2048 blocks
    const int xcd  = flat & 7;
    const int idx  = flat >> 3;     // 0..255
    const int mt   = (idx & 7) | (xcd << 3);   // 8 m-tiles per XCD -> 1 MB A-stripe in its L2
    const int nt   = idx >> 3;      // 0..31
    const int tile_m = mt * TM;
    const int tile_n = nt * TN;

    // staging: lane -> row (base + lane/8), slot (lane&7); source chunk XOR-swizzled
    const int srow8 = lane >> 3;
    const int gcol  = ((lane & 7) ^ srow8) * 16;
    const unsigned char* gA = A  + (size_t)(tile_m + wave * 32 + srow8) * K + gcol;
    const unsigned char* gB = Bt + (size_t)(tile_n + wave * 32 + srow8) * K + gcol;

    f32x4 acc[4][4];
    #pragma unroll
    for (int i = 0; i < 4; i++)
        #pragma unroll
        for (int j = 0; j < 4; j++) acc[i][j] = (f32x4){0.f, 0.f, 0.f, 0.f};

    const int sw = l16 & 7;
    const int slot_lo = ((2 * quad) ^ sw) * 16;
    const int slot_hi = ((2 * quad + 1) ^ sw) * 16;

    // stage one K-slab (byte offset kt) into buffer `buf`: 4 A-rows-of-8 + 4 B-rows-of-8
    auto stage = [&](int kt, int buf) {
        unsigned char* lab = la + buf * (TM * BK);
        unsigned char* lbb = lb + buf * (TN * BK);
        #pragma unroll
        for (int i = 0; i < 4; i++) {
            __builtin_amdgcn_global_load_lds(
                (const __attribute__((address_space(1))) void*)(gA + (size_t)(i * 8) * K + kt),
                (__attribute__((address_space(3))) void*)(lab + (wave * 32 + i * 8) * BK),
                16, 0, 0);
        }
        #pragma unroll
        for (int j = 0; j < 4; j++) {
            __builtin_amdgcn_global_load_lds(
                (const __attribute__((address_space(1))) void*)(gB + (size_t)(j * 8) * K + kt),
                (__attribute__((address_space(3))) void*)(lbb + (wave * 32 + j * 8) * BK),
                16, 0, 0);
        }
    };

    const int nkt = K / BK;   // 8
    stage(0, 0);
    int cur = 0;
    for (int t = 0; t < nkt; ++t) {
        if (t + 1 < nkt) {
            stage((t + 1) * BK, cur ^ 1);
            // 8 new loads outstanding; wait until only those remain -> slab t resident
            asm volatile("s_waitcnt vmcnt(8)" ::: "memory");
        } else {
            asm volatile("s_waitcnt vmcnt(0)" ::: "memory");
        }
        __builtin_amdgcn_s_barrier();   // all waves' slab-t loads now in LDS

        const unsigned char* pa_row = la + cur * (TM * BK) + (wm * 64 + l16) * BK;
        const unsigned char* pb_row = lb + cur * (TN * BK) + (wn * 64 + l16) * BK;

        i32x8 af[4];
        #pragma unroll
        for (int i = 0; i < 4; i++) {
            i32x4 lo = *(const i32x4*)(pa_row + i * 16 * BK + slot_lo);
            i32x4 hi = *(const i32x4*)(pa_row + i * 16 * BK + slot_hi);
            af[i] = __builtin_shufflevector(lo, hi, 0, 1, 2, 3, 4, 5, 6, 7);
        }
        i32x8 bf[4];
        #pragma unroll
        for (int j = 0; j < 4; j++) {
            i32x4 lo = *(const i32x4*)(pb_row + j * 16 * BK + slot_lo);
            i32x4 hi = *(const i32x4*)(pb_row + j * 16 * BK + slot_hi);
            bf[j] = __builtin_shufflevector(lo, hi, 0, 1, 2, 3, 4, 5, 6, 7);
        }
        __builtin_amdgcn_s_setprio(1);
        #pragma unroll
        for (int j = 0; j < 4; j++)
            #pragma unroll
            for (int i = 0; i < 4; i++)
                // swapped operands: D fragment transposed (row=n, col=m); scales swap too
                acc[i][j] = __builtin_amdgcn_mfma_scale_f32_16x16x128_f8f6f4(
                    bf[j], af[i], acc[i][j], 0, 0, 0, SCALE_B, 0, SCALE_A);
        __builtin_amdgcn_s_setprio(0);

        __builtin_amdgcn_s_barrier();   // buf `cur` free for reuse next iteration
        cur ^= 1;
    }

    // epilogue (transposed fragment): col = lane&15 -> m, row = quad*4 + rr -> n
    float xm[4];
    #pragma unroll
    for (int i = 0; i < 4; i++)
        xm[i] = x2[tile_m + wm * 64 + i * 16 + l16];
    #pragma unroll
    for (int j = 0; j < 4; j++) {
        const int n0 = tile_n + wn * 64 + j * 16 + quad * 4;
        const f32x4 sv = *(const f32x4*)(s + n0);
        const f32x4 bv = *(const f32x4*)(bias + n0);
        #pragma unroll
        for (int i = 0; i < 4; i++) {
            const int m = tile_m + wm * 64 + i * 16 + l16;
            f32x4 v;
            #pragma unroll
            for (int rr = 0; rr < 4; rr++)
                v[rr] = 2.f * acc[i][j][rr] - xm[i] - sv[rr] - bv[rr];
            __builtin_nontemporal_store(v, (f32x4*)(out + (size_t)m * N + n0));
        }
    }
}

extern "C" void kernel_launch(void* const* d_in, const int* in_sizes, int n_in,
                              void* d_out, int out_size, void* d_ws, size_t ws_size,
                              hipStream_t stream) {
    const float* x    = (const float*)d_in[0];
    const float* w    = (const float*)d_in[1];
    const float* bias = (const float*)d_in[2];
    float* out = (float*)d_out;

    const int C = in_sizes[2];              // 4096
    const int D = in_sizes[1] / C;          // 1024
    const int B = in_sizes[0] / D;          // 8192

    unsigned char* x8 = (unsigned char*)d_ws;              // B*D fp8 = 8 MB
    unsigned char* c8 = x8 + (size_t)B * D;                // C*D fp8 = 4 MB
    float* x2 = (float*)(c8 + (size_t)C * D);              // B fp32
    float* s  = x2 + B;                                    // C fp32

    hipMemsetAsync(s, 0, (size_t)C * sizeof(float), stream);   // s = 0; bias folded into gemm epilogue
    prep_x<<<B, 256, 0, stream>>>(x, (unsigned int*)x8, x2);
    prep_w<<<dim3(D / 64, C / 64), 256, 0, stream>>>(w, c8, s);
    const int nblocks = (B / TM) * (C / TN);
    gemm_bt<<<nblocks, 256, 0, stream>>>(x8, c8, x2, s, bias, out, B, C, D);
}

// Round 3
// 210.003 us; speedup vs baseline: 1.1096x; 1.0958x over previous
//
#include <hip/hip_runtime.h>

#define TM 128
#define TN 128
#define BK 128   // fp8 bytes per K-slab = one 16x16x128 MFMA k-step

typedef float f32x4 __attribute__((ext_vector_type(4)));
typedef int   i32x4 __attribute__((ext_vector_type(4)));
typedef int   i32x8 __attribute__((ext_vector_type(8)));

// E8M0 scales: value = 2^(byte-127). A-scale = 2^0; B holds cent*2^6, B-scale = 2^-6.
#define SCALE_A 127
#define SCALE_B 121

__device__ __forceinline__ unsigned char f2fp8(float f) {
    int p = __builtin_amdgcn_cvt_pk_fp8_f32(f, f, 0, false);
    return (unsigned char)(p & 0xff);
}

// ---- prep_x: x (B,1024) fp32 -> x8 fp8 row-major, x2[b] = sum(x^2) (exact fp32) ----
__global__ __launch_bounds__(256) void prep_x(const float* __restrict__ x,
                                              unsigned int* __restrict__ x8,
                                              float* __restrict__ x2) {
    const int b = blockIdx.x;
    const int t = threadIdx.x;
    const float4 v = ((const float4*)(x + (size_t)b * 1024))[t];
    float sum = v.x * v.x + v.y * v.y + v.z * v.z + v.w * v.w;
    int p = __builtin_amdgcn_cvt_pk_fp8_f32(v.x, v.y, 0, false);
    p = __builtin_amdgcn_cvt_pk_fp8_f32(v.z, v.w, p, true);
    x8[(size_t)b * 256 + t] = (unsigned int)p;
    #pragma unroll
    for (int o = 32; o > 0; o >>= 1) sum += __shfl_down(sum, o, 64);
    __shared__ float red[4];
    if ((t & 63) == 0) red[t >> 6] = sum;
    __syncthreads();
    if (t == 0) x2[b] = red[0] + red[1] + red[2] + red[3];
}

// ---- prep_w: cent[4q+r][d] = W[r*1024+d][q]; c8 = fp8(cent*64) (C x D row-major);
//      s[c] += ||cent_c||^2 (exact fp32, from fp32 W; s pre-zeroed by memset). ----
__global__ __launch_bounds__(256) void prep_w(const float* __restrict__ W,
                                              unsigned char* __restrict__ c8,
                                              float* __restrict__ s) {
    __shared__ float tile[64][65];
    __shared__ float cred[4][64];
    const int tid = threadIdx.x;
    const int tx = tid & 63;
    const int ty = tid >> 6;
    const int q0 = blockIdx.x * 64;
    const int e0 = blockIdx.y * 64;      // e = r*1024 + d
    const int r  = e0 >> 10;
    const int d0 = e0 & 1023;

    float csum = 0.f;
    #pragma unroll
    for (int p = 0; p < 16; p++) {
        const int er = p * 4 + ty;
        const float v = W[(size_t)(e0 + er) * 1024 + q0 + tx];
        tile[er][tx] = v;
        csum += v * v;
    }
    cred[ty][tx] = csum;
    __syncthreads();
    if (ty == 0) {
        atomicAdd(&s[4 * (q0 + tx) + r],
                  cred[0][tx] + cred[1][tx] + cred[2][tx] + cred[3][tx]);
    }
    #pragma unroll
    for (int p = 0; p < 16; p++) {
        const int q = q0 + p * 4 + ty;
        const float v = tile[tx][p * 4 + ty];
        c8[(size_t)(4 * q + r) * 1024 + d0 + tx] = f2fp8(v * 64.f);
    }
}

// ---- gemm_bt: out[m][n] = 2*sum_k A[m][k]*Bt[n][k] - x2[m] - s[n] - bias[n] ----
// R7 vs R6 (gemm 82 us, MfmaUtil 16%, unchanged by 2x occupancy -> NOT
// latency-bound; write-path-bound): R6's epilogue scattered 64x16B chunks
// per store instr (row-stride 16 KB) -> ~2.2 TB/s effective vs 6.6 TB/s the
// linear fill achieves on the same chip. FIX: LDS-staged epilogue transpose.
// After the K-loop the 64 KB LDS is dead; each wave dumps its fragments as
// 16x16 f32 tiles (contiguous 1 KB per ds_write instr, conflict-free), one
// __syncthreads, then threads re-read row-major and store 2 rows x 512 B
// contiguous per wave instr (perfect 128B-line coalescing). Main loop
// (counted-vmcnt dbuf pipeline, setprio, XOR-swizzled chunks) unchanged.
__global__ __launch_bounds__(256, 2) void gemm_bt(const unsigned char* __restrict__ A,
                                                  const unsigned char* __restrict__ Bt,
                                                  const float* __restrict__ x2,
                                                  const float* __restrict__ s,
                                                  const float* __restrict__ bias,
                                                  float* __restrict__ out,
                                                  int M, int N, int K) {
    __shared__ unsigned char smem[2 * TM * BK + 2 * TN * BK];   // 64 KB
    unsigned char* la = smem;                    // 32 KB (double-buffered A)
    unsigned char* lb = smem + 2 * TM * BK;      // 32 KB (double-buffered B)
    float* ftile = (float*)smem;                 // epilogue reuse: 128x128 f32 = 64 KB

    const int tid  = threadIdx.x;
    const int wave = tid >> 6;
    const int lane = tid & 63;
    const int quad = lane >> 4;
    const int l16  = lane & 15;
    const int wm   = wave & 1;     // m half: 64 rows
    const int wn   = wave >> 1;    // n half: 64 cols

    // XCD m-stripe swizzle (m-tiles = M/TM = 64, n-tiles = N/TN = 32)
    const int flat = blockIdx.x;    // 2048 blocks
    const int xcd  = flat & 7;
    const int idx  = flat >> 3;     // 0..255
    const int mt   = (idx & 7) | (xcd << 3);   // 8 m-tiles per XCD -> 1 MB A-stripe in its L2
    const int nt   = idx >> 3;      // 0..31
    const int tile_m = mt * TM;
    const int tile_n = nt * TN;

    // staging: lane -> row (base + lane/8), slot (lane&7); source chunk XOR-swizzled
    const int srow8 = lane >> 3;
    const int gcol  = ((lane & 7) ^ srow8) * 16;
    const unsigned char* gA = A  + (size_t)(tile_m + wave * 32 + srow8) * K + gcol;
    const unsigned char* gB = Bt + (size_t)(tile_n + wave * 32 + srow8) * K + gcol;

    f32x4 acc[4][4];
    #pragma unroll
    for (int i = 0; i < 4; i++)
        #pragma unroll
        for (int j = 0; j < 4; j++) acc[i][j] = (f32x4){0.f, 0.f, 0.f, 0.f};

    const int sw = l16 & 7;
    const int slot_lo = ((2 * quad) ^ sw) * 16;
    const int slot_hi = ((2 * quad + 1) ^ sw) * 16;

    // stage one K-slab (byte offset kt) into buffer `buf`: 4 A-rows-of-8 + 4 B-rows-of-8
    auto stage = [&](int kt, int buf) {
        unsigned char* lab = la + buf * (TM * BK);
        unsigned char* lbb = lb + buf * (TN * BK);
        #pragma unroll
        for (int i = 0; i < 4; i++) {
            __builtin_amdgcn_global_load_lds(
                (const __attribute__((address_space(1))) void*)(gA + (size_t)(i * 8) * K + kt),
                (__attribute__((address_space(3))) void*)(lab + (wave * 32 + i * 8) * BK),
                16, 0, 0);
        }
        #pragma unroll
        for (int j = 0; j < 4; j++) {
            __builtin_amdgcn_global_load_lds(
                (const __attribute__((address_space(1))) void*)(gB + (size_t)(j * 8) * K + kt),
                (__attribute__((address_space(3))) void*)(lbb + (wave * 32 + j * 8) * BK),
                16, 0, 0);
        }
    };

    const int nkt = K / BK;   // 8
    stage(0, 0);
    int cur = 0;
    for (int t = 0; t < nkt; ++t) {
        if (t + 1 < nkt) {
            stage((t + 1) * BK, cur ^ 1);
            // 8 new loads outstanding; wait until only those remain -> slab t resident
            asm volatile("s_waitcnt vmcnt(8)" ::: "memory");
        } else {
            asm volatile("s_waitcnt vmcnt(0)" ::: "memory");
        }
        __builtin_amdgcn_s_barrier();   // all waves' slab-t loads now in LDS

        const unsigned char* pa_row = la + cur * (TM * BK) + (wm * 64 + l16) * BK;
        const unsigned char* pb_row = lb + cur * (TN * BK) + (wn * 64 + l16) * BK;

        i32x8 af[4];
        #pragma unroll
        for (int i = 0; i < 4; i++) {
            i32x4 lo = *(const i32x4*)(pa_row + i * 16 * BK + slot_lo);
            i32x4 hi = *(const i32x4*)(pa_row + i * 16 * BK + slot_hi);
            af[i] = __builtin_shufflevector(lo, hi, 0, 1, 2, 3, 4, 5, 6, 7);
        }
        i32x8 bf[4];
        #pragma unroll
        for (int j = 0; j < 4; j++) {
            i32x4 lo = *(const i32x4*)(pb_row + j * 16 * BK + slot_lo);
            i32x4 hi = *(const i32x4*)(pb_row + j * 16 * BK + slot_hi);
            bf[j] = __builtin_shufflevector(lo, hi, 0, 1, 2, 3, 4, 5, 6, 7);
        }
        __builtin_amdgcn_s_setprio(1);
        #pragma unroll
        for (int j = 0; j < 4; j++)
            #pragma unroll
            for (int i = 0; i < 4; i++)
                // swapped operands: D fragment transposed (row=n, col=m); scales swap too
                acc[i][j] = __builtin_amdgcn_mfma_scale_f32_16x16x128_f8f6f4(
                    bf[j], af[i], acc[i][j], 0, 0, 0, SCALE_B, 0, SCALE_A);
        __builtin_amdgcn_s_setprio(0);

        __builtin_amdgcn_s_barrier();   // buf `cur` free for reuse next iteration
        cur ^= 1;
    }

    // ---- epilogue: finish math in regs, LDS transpose, coalesced stores ----
    // fragment (transposed): m = tile-local row = l16, n = quad*4 + rr
    float xm[4];
    #pragma unroll
    for (int i = 0; i < 4; i++)
        xm[i] = x2[tile_m + wm * 64 + i * 16 + l16];
    #pragma unroll
    for (int j = 0; j < 4; j++) {
        const int n0 = tile_n + wn * 64 + j * 16 + quad * 4;
        const f32x4 sv = *(const f32x4*)(s + n0);
        const f32x4 bv = *(const f32x4*)(bias + n0);
        #pragma unroll
        for (int i = 0; i < 4; i++) {
            f32x4 v;
            #pragma unroll
            for (int rr = 0; rr < 4; rr++)
                v[rr] = 2.f * acc[i][j][rr] - xm[i] - sv[rr] - bv[rr];
            // 16x16 tile (ti = wm*4+i, tj = wn*4+j), stored as 1 KB contiguous:
            // float idx = tile*256 + row(l16)*16 + chunk(quad)*4
            const int ti = wm * 4 + i;
            const int tj = wn * 4 + j;
            *(f32x4*)(ftile + (ti * 8 + tj) * 256 + l16 * 16 + quad * 4) = v;
        }
    }
    __syncthreads();
    // read back row-major: wave covers 2 rows x 512 B contiguous per iteration
    #pragma unroll
    for (int it = 0; it < 16; ++it) {
        const int r = it * 8 + (tid >> 5);   // 0..127
        const int c = tid & 31;              // f32x4 chunk within row (n = 4c)
        const f32x4 v = *(const f32x4*)(ftile + ((r >> 4) * 8 + (c >> 2)) * 256
                                        + (r & 15) * 16 + (c & 3) * 4);
        __builtin_nontemporal_store(v, (f32x4*)(out + (size_t)(tile_m + r) * N + tile_n + c * 4));
    }
}

extern "C" void kernel_launch(void* const* d_in, const int* in_sizes, int n_in,
                              void* d_out, int out_size, void* d_ws, size_t ws_size,
                              hipStream_t stream) {
    const float* x    = (const float*)d_in[0];
    const float* w    = (const float*)d_in[1];
    const float* bias = (const float*)d_in[2];
    float* out = (float*)d_out;

    const int C = in_sizes[2];              // 4096
    const int D = in_sizes[1] / C;          // 1024
    const int B = in_sizes[0] / D;          // 8192

    unsigned char* x8 = (unsigned char*)d_ws;              // B*D fp8 = 8 MB
    unsigned char* c8 = x8 + (size_t)B * D;                // C*D fp8 = 4 MB
    float* x2 = (float*)(c8 + (size_t)C * D);              // B fp32
    float* s  = x2 + B;                                    // C fp32

    hipMemsetAsync(s, 0, (size_t)C * sizeof(float), stream);   // s = 0; bias folded into gemm epilogue
    prep_x<<<B, 256, 0, stream>>>(x, (unsigned int*)x8, x2);
    prep_w<<<dim3(D / 64, C / 64), 256, 0, stream>>>(w, c8, s);
    const int nblocks = (B / TM) * (C / TN);
    gemm_bt<<<nblocks, 256, 0, stream>>>(x8, c8, x2, s, bias, out, B, C, D);
}